// Round 2
// baseline (117.144 us; speedup 1.0000x reference)
//
#include <hip/hip_runtime.h>

// MFHawkes: B=4, L=2048, K=100000, D=64
// Algebraic collapse (validated R1, absmax 0.0):
//   lam_i   = |ab * exp(-ab*t_i) * (e_i . P_i) + u_i| + 1e-6,
//             P_i = sum_{j<i} e_j * exp(ab*t_j) * m_j       (D-vector prefix sum)
//   out[b]  = sum_i [-log(lam_i) + u_i*horizon] + (sum_i e_i) . V,
//             V   = sum_j e_j * (1 - exp(-ab*(t_last - t_j)))
//
// R2: single fused kernel. Cross-chunk prefix via chained-scan with
// device-scope flags in ws (128 blocks, all co-resident on 256 CUs; waits are
// acyclic -> no deadlock). E tile lives in LDS across phases (no HBM
// round-trip). Block (b, NC-1) collects per-chunk contribs and writes out[b]
// directly -> no memset, no atomics on d_out. Flags checked ==1 (ws poison is
// 0xAAAAAAAA, never 1).

#define BB 4
#define LL 2048
#define DD 64
#define CL 64            // chunk length
#define NC (LL / CL)     // 32 chunks per batch

#define LOADF(p)     __hip_atomic_load((p), __ATOMIC_RELAXED, __HIP_MEMORY_SCOPE_AGENT)
#define STOREF(p, v) __hip_atomic_store((p), (v), __ATOMIC_RELAXED, __HIP_MEMORY_SCOPE_AGENT)

__global__ __launch_bounds__(64) void fused_hawkes(
    const int* __restrict__ ids, const float* __restrict__ times,
    const float* __restrict__ mask, const float* __restrict__ emb,
    const float* __restrict__ u_table, const float* __restrict__ beta,
    float* __restrict__ S, float* __restrict__ Ep, float* __restrict__ Vp,
    float* __restrict__ Ctr, int* __restrict__ flag1, int* __restrict__ flag2,
    float* __restrict__ out)
{
    __shared__ float E [CL][DD + 1];   // +1 pad: 2-way alias only (free)
    __shared__ float LP[CL][DD + 1];
    __shared__ float wm[CL];

    const int blk = blockIdx.x;
    const int b = blk / NC, c = blk % NC;
    const int lane = threadIdx.x;      // 0..63
    const int j0 = c * CL;
    const int rec = b * NC + c;

    const float ab = fabsf(beta[0]);
    const float tl = times[b * LL + LL - 1] * 1e-4f;
    const float t1 = times[b * LL + 1] * 1e-4f;
    const float horizon = tl - t1;
    const float ce = expf(-ab * tl);   // exp(-ab * t_last)

    // per-lane row scalars (row = j0 + lane), coalesced; broadcast via shfl
    const int   myid = ids  [b * LL + j0 + lane];
    const float myt  = times[b * LL + j0 + lane] * 1e-4f;
    const float mym  = mask [b * LL + j0 + lane];
    const float myuk = fabsf(u_table[myid]);     // random 4B gather, L2/L3

    wm[lane] = expf(ab * myt) * mym;

    // ---- gather phase: emb rows -> LDS tile + chunk partial sums ----------
    float s = 0.f, ep = 0.f, vp = 0.f;
#pragma unroll 16
    for (int jj = 0; jj < CL; ++jj) {
        const int   id = __shfl(myid, jj);
        const float t  = __shfl(myt,  jj);
        const float m  = __shfl(mym,  jj);
        const float e  = emb[(long)id * DD + lane];  // 256B row, coalesced
        const float w  = expf(ab * t);               // in [1, 1.105]
        E[jj][lane] = e;
        s  += e * w * m;
        ep += e;
        vp += e * (1.f - ce * w);
    }

    // ---- publish chunk record, then release flag1 -------------------------
    STOREF(&S [rec * DD + lane], s);
    STOREF(&Ep[rec * DD + lane], ep);
    STOREF(&Vp[rec * DD + lane], vp);
    __threadfence();                                 // device-scope release
    if (lane == 0)
        __hip_atomic_store(&flag1[rec], 1, __ATOMIC_RELEASE, __HIP_MEMORY_SCOPE_AGENT);

    // ---- lookback: exclusive cross-chunk offset ---------------------------
    for (int cc = 0; cc < c; ++cc)
        while (__hip_atomic_load(&flag1[b * NC + cc], __ATOMIC_ACQUIRE,
                                 __HIP_MEMORY_SCOPE_AGENT) != 1)
            __builtin_amdgcn_s_sleep(1);

    float run = 0.f;
#pragma unroll 8
    for (int cc = 0; cc < c; ++cc)                   // independent loads, MLP
        run += LOADF(&S[(b * NC + cc) * DD + lane]);

    __syncthreads();

    // ---- intra-chunk exclusive scan (lane = dim d) ------------------------
#pragma unroll 8
    for (int i = 0; i < CL; ++i) {
        LP[i][lane] = run;
        run += E[i][lane] * wm[i];                   // wm[i]: LDS broadcast
    }
    __syncthreads();

    // ---- dot phase (lane = row): e_i . P_i --------------------------------
    float acc = 0.f;
#pragma unroll
    for (int k = 0; k < DD; ++k)
        acc += E[lane][k] * LP[lane][k];

    const float s1  = ab * expf(-ab * myt) * acc;
    const float lam = fabsf(s1 + myuk) + 1e-6f;
    const float rowContrib = -logf(lam) + myuk * horizon;

    if (c != NC - 1) {
        // reduce own 64 row-contribs, publish scalar + flag2
        float v = rowContrib;
#pragma unroll
        for (int off = 32; off > 0; off >>= 1)
            v += __shfl_xor(v, off);
        if (lane == 0) {
            STOREF(&Ctr[rec], v);
            __threadfence();
            __hip_atomic_store(&flag2[rec], 1, __ATOMIC_RELEASE, __HIP_MEMORY_SCOPE_AGENT);
        }
    } else {
        // summer block: wait all other chunks' contribs
        for (int cc = 0; cc < NC - 1; ++cc)
            while (__hip_atomic_load(&flag2[b * NC + cc], __ATOMIC_ACQUIRE,
                                     __HIP_MEMORY_SCOPE_AGENT) != 1)
                __builtin_amdgcn_s_sleep(1);

        // per-lane: (sum_c Ep) * (sum_c Vp) for dim=lane  (flag1 of all c
        // already acquired during lookback; own chunk in registers)
        float et = 0.f, vt = 0.f;
#pragma unroll 8
        for (int cc = 0; cc < NC; ++cc) {
            et += LOADF(&Ep[(b * NC + cc) * DD + lane]);
            vt += LOADF(&Vp[(b * NC + cc) * DD + lane]);
        }
        // lane cc<NC-1 picks up chunk cc's scalar contrib
        float oc = (lane < NC - 1) ? LOADF(&Ctr[b * NC + lane]) : 0.f;

        float v = rowContrib + et * vt + oc;
#pragma unroll
        for (int off = 32; off > 0; off >>= 1)
            v += __shfl_xor(v, off);
        if (lane == 0)
            out[b] = v;                              // sole writer, plain store
    }
}

// ---------------------------------------------------------------------------
extern "C" void kernel_launch(void* const* d_in, const int* in_sizes, int n_in,
                              void* d_out, int out_size, void* d_ws, size_t ws_size,
                              hipStream_t stream)
{
    const int*   ids     = (const int*)  d_in[0];
    const float* times   = (const float*)d_in[1];
    const float* mask    = (const float*)d_in[2];
    const float* emb     = (const float*)d_in[3];
    const float* u_table = (const float*)d_in[4];
    const float* beta    = (const float*)d_in[5];
    float* outp = (float*)d_out;

    float* ws    = (float*)d_ws;
    float* S     = ws;                       // BB*NC*DD = 8192 floats
    float* Ep    = S   + BB * NC * DD;       // 8192
    float* Vp    = Ep  + BB * NC * DD;       // 8192
    float* Ctr   = Vp  + BB * NC * DD;       // BB*NC = 128
    int*   flag1 = (int*)(Ctr + BB * NC);    // 128
    int*   flag2 = flag1 + BB * NC;          // 128

    fused_hawkes<<<BB * NC, 64, 0, stream>>>(ids, times, mask, emb, u_table,
                                             beta, S, Ep, Vp, Ctr,
                                             flag1, flag2, outp);
}